// Round 12
// baseline (388.340 us; speedup 1.0000x reference)
//
#include <hip/hip_runtime.h>
#include <hip/hip_bf16.h>
#include <math.h>

#define N_NODES 20000
#define N_EDGES 320000

typedef _Float16 f16x8 __attribute__((ext_vector_type(8)));
typedef _Float16 h2 __attribute__((ext_vector_type(2)));
typedef float f32x4 __attribute__((ext_vector_type(4)));

__device__ __forceinline__ unsigned short f2h_bits(float f) {
    _Float16 h = (_Float16)f;            // RNE f32->f16
    return __builtin_bit_cast(unsigned short, h);
}

// async global->LDS DMA, 16B per lane; LDS dest = wave-uniform base + lane*16
typedef const unsigned int __attribute__((address_space(1)))* gas_ptr;
typedef unsigned int __attribute__((address_space(3)))* las_ptr;
__device__ __forceinline__ void gld16(const unsigned short* g, unsigned short* l) {
    __builtin_amdgcn_global_load_lds((gas_ptr)(const void*)g, (las_ptr)(void*)l, 16, 0, 0);
}

// ---------------------------------------------------------------------------
// CSR build
// ---------------------------------------------------------------------------
__global__ void zero_int_kernel(int* __restrict__ p, int n) {
    int i = blockIdx.x * blockDim.x + threadIdx.x;
    if (i < n) p[i] = 0;
}

__global__ void count_deg_kernel(const int* __restrict__ dst, int* __restrict__ deg, int E) {
    int i = blockIdx.x * blockDim.x + threadIdx.x;
    if (i < E) atomicAdd(&deg[dst[i]], 1);
}

#define SCAN_T 1024
#define SCAN_C 20   // ceil(20000/1024)
__global__ __launch_bounds__(1024) void scan_kernel(const int* __restrict__ deg,
                                                    int* __restrict__ offs,
                                                    int* __restrict__ cursor, int n) {
    __shared__ int sd[SCAN_T];
    int t = threadIdx.x;
    int base = t * SCAN_C;
    int vex[SCAN_C];
    int run = 0;
#pragma unroll
    for (int k = 0; k < SCAN_C; ++k) {
        int i = base + k;
        int d = (i < n) ? deg[i] : 0;
        vex[k] = run;
        run += d;
    }
    sd[t] = run;
    __syncthreads();
    for (int off = 1; off < SCAN_T; off <<= 1) {
        int x = (t >= off) ? sd[t - off] : 0;
        __syncthreads();
        sd[t] += x;
        __syncthreads();
    }
    int excl = sd[t] - run;
#pragma unroll
    for (int k = 0; k < SCAN_C; ++k) {
        int i = base + k;
        if (i < n) { int e = excl + vex[k]; offs[i] = e; cursor[i] = e; }
    }
    if (t == SCAN_T - 1) offs[n] = sd[t];
}

__global__ void scatter_kernel(const int* __restrict__ src, const int* __restrict__ dst,
                               int* __restrict__ cursor, int* __restrict__ csr_src, int E) {
    int i = blockIdx.x * blockDim.x + threadIdx.x;
    if (i < E) {
        int pos = atomicAdd(&cursor[dst[i]], 1);
        csr_src[pos] = src[i];
    }
}

// ---------------------------------------------------------------------------
// unified prep: 9 weight transposes (fp32 [K][D] -> f16 [D][K], output-major)
// + x fp32->f16 conversion, in ONE launch.
// ---------------------------------------------------------------------------
struct PrepJobs {
    const float* W[9];
    unsigned short* Wt[9];
    int K[9];
    int D[9];
    int beg[10];
    const float* x;            // fp32 input
    unsigned short* xh;        // f16 output
    int nconv4;                // n/4 float4 groups
};
__global__ void prep_kernel(PrepJobs jb) {
    int i = blockIdx.x * blockDim.x + threadIdx.x;
    int nt = jb.beg[9];
    if (i < nt) {
        int job = 0;
        while (i >= jb.beg[job + 1]) ++job;
        int local = i - jb.beg[job];
        int D = jb.D[job], K = jb.K[job];
        int d = local / K, k = local - d * K;
        jb.Wt[job][local] = f2h_bits(jb.W[job][(size_t)k * D + d]);
    } else {
        int c = i - nt;
        if (c < jb.nconv4) {
            int base = c * 4;
            float4 v = *(const float4*)(jb.x + base);
            uint2 pk;
            pk.x = (unsigned int)f2h_bits(v.x) | ((unsigned int)f2h_bits(v.y) << 16);
            pk.y = (unsigned int)f2h_bits(v.z) | ((unsigned int)f2h_bits(v.w) << 16);
            *(uint2*)(jb.xh + base) = pk;
        }
    }
}

// ---------------------------------------------------------------------------
// fused 3-in-1 f16 MFMA GEMM, BK=64 DMA-staged, XCD-aware remap:
//   [xl | xr | seed] = A[M,K] @ Btcat[3D,K]^T  (bias bs+bc on seed segment)
// 128x128 tile, BK=64 -> 64 MFMA per barrier pair (halved drain count vs
// BK=32); staging via global_load_lds width=16 (zero VGPR cost); LDS is
// K-MAJOR chunk order (part*128+row) — matches DMA contiguity AND gives
// consecutive-t rows a 4-bank shift (2-way aliasing = free, m136).
// Operands swapped: mfma(Bt_frag, A_frag) -> packed 8B/16B epilogue stores.
// ---------------------------------------------------------------------------
template <int SEED_F32>
__global__ __launch_bounds__(256) void gemm3_kernel(
        const unsigned short* __restrict__ A,    // [M][K] f16
        const unsigned short* __restrict__ Bt,   // [3D][K] f16 (Wl^T|Wr^T|Ws^T)
        unsigned short* __restrict__ xlh,        // [M][D] f16
        unsigned short* __restrict__ xrh,        // [M][D] f16
        unsigned short* __restrict__ seedh,      // [M][D] f16 (SEED_F32==0)
        float* __restrict__ seedf,               // [M][D] fp32 (SEED_F32==1)
        const float* __restrict__ b1,
        const float* __restrict__ b2,
        int M, int K, int D) {
    __shared__ __align__(16) unsigned short Asl[128 * 64];
    __shared__ __align__(16) unsigned short Bsl[128 * 64];

    int NC = (3 * D) >> 7;               // column tiles
    int MT = (M + 127) >> 7;             // M tiles
    int g = blockIdx.x;
    int xcd = g & 7, slot = g >> 3;
    int m_local = slot / NC, c = slot - m_local * NC;
    int mt = m_local * 8 + xcd;
    if (mt >= MT) return;                // block-uniform -> safe before barriers

    int tid = threadIdx.x;
    int wave = tid >> 6, lane = tid & 63;
    int q = lane >> 4, t = lane & 15;
    int wm = (wave & 1) * 64, wn = (wave >> 1) * 64;
    int bm = mt << 7;
    int bn_all = c << 7;
    int seg = bn_all / D;                // D multiple of 128 -> block-uniform
    int bn = bn_all - seg * D;

    // acc[jn][im]: value reg r at lane (q,t) = C[m = im*16 + t][n = jn*16 + q*4 + r]
    f32x4 acc[4][4];
#pragma unroll
    for (int i = 0; i < 4; ++i)
#pragma unroll
        for (int j = 0; j < 4; ++j) acc[i][j] = (f32x4){0.f, 0.f, 0.f, 0.f};

    for (int k0 = 0; k0 < K; k0 += 64) {
        // chunk id c = p*128 + row  (p = k-granule 0..7, row 0..127)
        // round rnd covers c in [rnd*256, rnd*256+256): row = c&127, p = c>>7.
        // LDS addr = c*16B -> k-major [p][row] layout.
#pragma unroll
        for (int rnd = 0; rnd < 4; ++rnd) {
            int ch = rnd * 256 + tid;
            int row = ch & 127, p = ch >> 7;
            int gr = bm + row; if (gr >= M) gr = M - 1;   // clamp, rows>=M unused
            gld16(A + (size_t)gr * K + k0 + p * 8,
                  Asl + (rnd * 256 + wave * 64) * 8);     // wave-uniform base
        }
#pragma unroll
        for (int rnd = 0; rnd < 4; ++rnd) {
            int ch = rnd * 256 + tid;
            int row = ch & 127, p = ch >> 7;
            gld16(Bt + (size_t)(bn_all + row) * K + k0 + p * 8,
                  Bsl + (rnd * 256 + wave * 64) * 8);
        }
        __syncthreads();   // drains vmcnt -> DMA complete

#pragma unroll
        for (int h = 0; h < 2; ++h) {     // two K=32 halves
            f16x8 an[4], am[4];
#pragma unroll
            for (int jn = 0; jn < 4; ++jn)
                an[jn] = *(const f16x8*)(Bsl + (((h << 2) + q) * 128 + wn + jn * 16 + t) * 8);
#pragma unroll
            for (int im = 0; im < 4; ++im)
                am[im] = *(const f16x8*)(Asl + (((h << 2) + q) * 128 + wm + im * 16 + t) * 8);
#pragma unroll
            for (int jn = 0; jn < 4; ++jn)
#pragma unroll
                for (int im = 0; im < 4; ++im)
                    acc[jn][im] = __builtin_amdgcn_mfma_f32_16x16x32_f16(an[jn], am[im], acc[jn][im], 0, 0, 0);
        }
        __syncthreads();   // protect LDS before next staging
    }

    // epilogue: per lane, 4 consecutive columns per (jn,im) -> packed stores
#pragma unroll
    for (int jn = 0; jn < 4; ++jn) {
        int n0 = bn + wn + jn * 16 + q * 4;
        float bx = 0.f, by = 0.f, bz = 0.f, bw = 0.f;
        if (seg == 2) {
            float4 bb1 = *(const float4*)(b1 + n0);
            float4 bb2 = *(const float4*)(b2 + n0);
            bx = bb1.x + bb2.x; by = bb1.y + bb2.y;
            bz = bb1.z + bb2.z; bw = bb1.w + bb2.w;
        }
#pragma unroll
        for (int im = 0; im < 4; ++im) {
            int m = bm + wm + im * 16 + t;
            if (m < M) {
                float v0 = acc[jn][im][0] + bx;
                float v1 = acc[jn][im][1] + by;
                float v2 = acc[jn][im][2] + bz;
                float v3 = acc[jn][im][3] + bw;
                size_t idx = (size_t)m * D + n0;
                if (seg == 2 && SEED_F32) {
                    *(float4*)(seedf + idx) = make_float4(v0, v1, v2, v3);
                } else {
                    uint2 pk;
                    pk.x = (unsigned int)f2h_bits(v0) | ((unsigned int)f2h_bits(v1) << 16);
                    pk.y = (unsigned int)f2h_bits(v2) | ((unsigned int)f2h_bits(v3) << 16);
                    unsigned short* dstp = (seg == 0) ? xlh : (seg == 1) ? xrh : seedh;
                    *(uint2*)(dstp + idx) = pk;
                }
            }
        }
    }
}

// ---------------------------------------------------------------------------
// fused per-node (R10 variant — best measured: 53.1 µs, VGPR 44):
// edge scores + online softmax + aggregation + skip. One wave per node,
// 2 nodes per 128-thread block; 4 edges/iter; f16 packed score math +
// f32-acc dot2; 11-shuffle butterfly; index-only prefetch.
// ---------------------------------------------------------------------------
template <int D, int SEED_H, int WRITE_H, int RELU>
__global__ __launch_bounds__(128) void fused_agg_kernel(
        const unsigned short* __restrict__ xl,
        const unsigned short* __restrict__ xr,
        const float* __restrict__ att,
        const int* __restrict__ offs,
        const int* __restrict__ csr_src,
        const unsigned short* __restrict__ seedh,
        const float* __restrict__ seedf,
        float* __restrict__ outf,
        unsigned short* __restrict__ outh) {
    constexpr int VPL = D / 64;
    constexpr int HP = VPL / 2;
    typedef _Float16 hvec __attribute__((ext_vector_type(VPL)));

    int wave = threadIdx.x >> 6, lane = threadIdx.x & 63;
    int n = blockIdx.x * 2 + wave;
    if (n >= N_NODES) return;
    int beg = offs[n], end = offs[n + 1];

    h2 xr_h[HP], att_h[HP];
    hvec xrv = *(const hvec*)(xr + (size_t)n * D + lane * VPL);
#pragma unroll
    for (int pp = 0; pp < HP; ++pp) {
        xr_h[pp] = (h2){xrv[2 * pp], xrv[2 * pp + 1]};
        att_h[pp] = (h2){(_Float16)att[lane * VPL + 2 * pp],
                         (_Float16)att[lane * VPL + 2 * pp + 1]};
    }

    float acc[VPL];
#pragma unroll
    for (int v = 0; v < VPL; ++v) acc[v] = 0.f;
    float m = -INFINITY, s = 0.f;

    const _Float16 c02 = (_Float16)0.2f;
    int lb0 = lane & 1;
    int lb1 = lane & 2;

    int nfull = (end - beg) >> 2;
    int j = beg;
    int i0 = 0, i1 = 0, i2 = 0, i3 = 0;
    if (nfull > 0) {
        i0 = csr_src[beg]; i1 = csr_src[beg + 1];
        i2 = csr_src[beg + 2]; i3 = csr_src[beg + 3];
    }
    for (int b = 0; b < nfull; ++b) {
        int s0 = i0, s1 = i1, s2 = i2, s3 = i3;
        int jn4 = j + 4;
        if (b + 1 < nfull) {            // prefetch next batch's indices
            i0 = csr_src[jn4]; i1 = csr_src[jn4 + 1];
            i2 = csr_src[jn4 + 2]; i3 = csr_src[jn4 + 3];
        }
        hvec x0 = *(const hvec*)(xl + (size_t)s0 * D + lane * VPL);
        hvec x1 = *(const hvec*)(xl + (size_t)s1 * D + lane * VPL);
        hvec x2 = *(const hvec*)(xl + (size_t)s2 * D + lane * VPL);
        hvec x3 = *(const hvec*)(xl + (size_t)s3 * D + lane * VPL);
        float p0 = 0.f, p1 = 0.f, p2 = 0.f, p3 = 0.f;
#pragma unroll
        for (int pp = 0; pp < HP; ++pp) {
            h2 a0 = (h2){x0[2 * pp], x0[2 * pp + 1]};
            h2 a1 = (h2){x1[2 * pp], x1[2 * pp + 1]};
            h2 a2 = (h2){x2[2 * pp], x2[2 * pp + 1]};
            h2 a3 = (h2){x3[2 * pp], x3[2 * pp + 1]};
            h2 z0 = a0 + xr_h[pp];
            h2 z1 = a1 + xr_h[pp];
            h2 z2 = a2 + xr_h[pp];
            h2 z3 = a3 + xr_h[pp];
            h2 l0 = __builtin_elementwise_max(z0, z0 * c02);   // leaky_relu
            h2 l1 = __builtin_elementwise_max(z1, z1 * c02);
            h2 l2 = __builtin_elementwise_max(z2, z2 * c02);
            h2 l3 = __builtin_elementwise_max(z3, z3 * c02);
#if __has_builtin(__builtin_amdgcn_fdot2)
            p0 = __builtin_amdgcn_fdot2(l0, att_h[pp], p0, false);
            p1 = __builtin_amdgcn_fdot2(l1, att_h[pp], p1, false);
            p2 = __builtin_amdgcn_fdot2(l2, att_h[pp], p2, false);
            p3 = __builtin_amdgcn_fdot2(l3, att_h[pp], p3, false);
#else
            p0 += (float)l0.x * (float)att_h[pp].x + (float)l0.y * (float)att_h[pp].y;
            p1 += (float)l1.x * (float)att_h[pp].x + (float)l1.y * (float)att_h[pp].y;
            p2 += (float)l2.x * (float)att_h[pp].x + (float)l2.y * (float)att_h[pp].y;
            p3 += (float)l3.x * (float)att_h[pp].x + (float)l3.y * (float)att_h[pp].y;
#endif
        }
        // butterfly tree: stride 1 (4->2 regs), stride 2 (2->1), strides 4..32
        float k0 = lb0 ? p1 : p0, sn0 = lb0 ? p0 : p1;
        float k1 = lb0 ? p3 : p2, sn1 = lb0 ? p2 : p3;
        k0 += __shfl_xor(sn0, 1, 64);
        k1 += __shfl_xor(sn1, 1, 64);
        float k = lb1 ? k1 : k0, sn = lb1 ? k0 : k1;
        k += __shfl_xor(sn, 2, 64);
        k += __shfl_xor(k, 4, 64);
        k += __shfl_xor(k, 8, 64);
        k += __shfl_xor(k, 16, 64);
        k += __shfl_xor(k, 32, 64);
        // lane l holds full score of edge (l&3); broadcast all four
        float q0 = __shfl(k, 0, 64);
        float q1 = __shfl(k, 1, 64);
        float q2 = __shfl(k, 2, 64);
        float q3 = __shfl(k, 3, 64);

        float mn = fmaxf(m, fmaxf(fmaxf(q0, q1), fmaxf(q2, q3)));
        float sc = __expf(m - mn);           // first iter: exp(-inf)=0
        float e0 = __expf(q0 - mn);
        float e1 = __expf(q1 - mn);
        float e2 = __expf(q2 - mn);
        float e3 = __expf(q3 - mn);
        s = s * sc + e0 + e1 + e2 + e3;
#pragma unroll
        for (int v = 0; v < VPL; ++v)
            acc[v] = acc[v] * sc + e0 * (float)x0[v] + e1 * (float)x1[v]
                                 + e2 * (float)x2[v] + e3 * (float)x3[v];
        m = mn;
        j = jn4;
    }
    for (; j < end; ++j) {   // tail (0-3 edges)
        int s0 = csr_src[j];
        hvec x0 = *(const hvec*)(xl + (size_t)s0 * D + lane * VPL);
        float p0 = 0.f;
#pragma unroll
        for (int pp = 0; pp < HP; ++pp) {
            h2 a0 = (h2){x0[2 * pp], x0[2 * pp + 1]};
            h2 z0 = a0 + xr_h[pp];
            h2 l0 = __builtin_elementwise_max(z0, z0 * c02);
#if __has_builtin(__builtin_amdgcn_fdot2)
            p0 = __builtin_amdgcn_fdot2(l0, att_h[pp], p0, false);
#else
            p0 += (float)l0.x * (float)att_h[pp].x + (float)l0.y * (float)att_h[pp].y;
#endif
        }
#pragma unroll
        for (int o = 32; o > 0; o >>= 1) p0 += __shfl_xor(p0, o, 64);
        float mn = fmaxf(m, p0);
        float sc = __expf(m - mn);
        float e0 = __expf(p0 - mn);
        s = s * sc + e0;
#pragma unroll
        for (int v = 0; v < VPL; ++v) acc[v] = acc[v] * sc + e0 * (float)x0[v];
        m = mn;
    }

    float sinv = 1.0f / (s + 1e-16f);
    size_t base = (size_t)n * D + lane * VPL;
    float sd[VPL];
    if (SEED_H) {
        hvec sv = *(const hvec*)(seedh + base);
#pragma unroll
        for (int v = 0; v < VPL; ++v) sd[v] = (float)sv[v];
    } else {
#pragma unroll
        for (int v = 0; v < VPL; ++v) sd[v] = seedf[base + v];
    }
#pragma unroll
    for (int v = 0; v < VPL; ++v) {
        float val = sd[v] + acc[v] * sinv;
        if (RELU) val = fmaxf(val, 0.f);
        if (WRITE_H) outh[base + v] = f2h_bits(val);
        else         outf[base + v] = val;
    }
}

// ---------------------------------------------------------------------------
// host-side layer driver
// ---------------------------------------------------------------------------
static void run_layer(const unsigned short* hact, int K, int D,
                      const unsigned short* Wcat,
                      const float* att, const float* bc, const float* bs,
                      unsigned short* xlh, unsigned short* xrh,
                      unsigned short* seedh, float* seedf,
                      const int* offs, const int* csr_src,
                      float* outf, unsigned short* outh, int final_layer,
                      hipStream_t stream) {
    int NC = 3 * D / 128;
    int MT = (N_NODES + 127) / 128;
    int nblk = 8 * ((MT + 7) / 8) * NC;   // XCD-swizzled 1D grid
    if (final_layer)
        hipLaunchKernelGGL((gemm3_kernel<1>), dim3(nblk), dim3(256), 0, stream, hact, Wcat,
                           xlh, xrh, (unsigned short*)nullptr, seedf, bs, bc, N_NODES, K, D);
    else
        hipLaunchKernelGGL((gemm3_kernel<0>), dim3(nblk), dim3(256), 0, stream, hact, Wcat,
                           xlh, xrh, seedh, (float*)nullptr, bs, bc, N_NODES, K, D);

    dim3 agrid((N_NODES + 1) / 2);
    if (D == 512) {
        hipLaunchKernelGGL((fused_agg_kernel<512, 1, 1, 1>), agrid, dim3(128), 0, stream,
                           xlh, xrh, att, offs, csr_src, seedh, (const float*)nullptr,
                           (float*)nullptr, outh);
    } else if (D == 256) {
        hipLaunchKernelGGL((fused_agg_kernel<256, 1, 1, 1>), agrid, dim3(128), 0, stream,
                           xlh, xrh, att, offs, csr_src, seedh, (const float*)nullptr,
                           (float*)nullptr, outh);
    } else {
        hipLaunchKernelGGL((fused_agg_kernel<128, 0, 0, 0>), agrid, dim3(128), 0, stream,
                           xlh, xrh, att, offs, csr_src, (const unsigned short*)nullptr, seedf,
                           outf, (unsigned short*)nullptr);
    }
}

extern "C" void kernel_launch(void* const* d_in, const int* in_sizes, int n_in,
                              void* d_out, int out_size, void* d_ws, size_t ws_size,
                              hipStream_t stream) {
    const float* x = (const float*)d_in[0];
    const int* ei = (const int*)d_in[1];
    const int* src = ei;
    const int* dst = ei + N_EDGES;

    const float* Wl1 = (const float*)d_in[2];
    const float* Wr1 = (const float*)d_in[3];
    const float* att1 = (const float*)d_in[4];
    const float* bc1 = (const float*)d_in[5];
    const float* Ws1 = (const float*)d_in[6];
    const float* bs1 = (const float*)d_in[7];
    const float* Wl2 = (const float*)d_in[8];
    const float* Wr2 = (const float*)d_in[9];
    const float* att2 = (const float*)d_in[10];
    const float* bc2 = (const float*)d_in[11];
    const float* Ws2 = (const float*)d_in[12];
    const float* bs2 = (const float*)d_in[13];
    const float* Wl3 = (const float*)d_in[14];
    const float* Wr3 = (const float*)d_in[15];
    const float* att3 = (const float*)d_in[16];
    const float* bc3 = (const float*)d_in[17];
    const float* Ws3 = (const float*)d_in[18];
    const float* bs3 = (const float*)d_in[19];

    // workspace carve
    const size_t NF = (size_t)N_NODES * 512;
    const size_t NH = (size_t)N_NODES * 256;
    unsigned short* xlh   = (unsigned short*)d_ws;      // N x 512 f16 (reused per layer)
    unsigned short* xrh   = xlh + NF;
    unsigned short* seedh = xrh + NF;                   // N x 512 f16 (layers 1-2)
    unsigned short* xhf   = seedh + NF;                 // x as f16: N x 256
    unsigned short* h1h   = xhf + NH;                   // layer1 out: N x 512
    unsigned short* h2h   = h1h + NF;                   // layer2 out: N x 256
    unsigned short* Wcat1 = h2h + NH;                   // 3 x 512 x 256
    unsigned short* Wcat2 = Wcat1 + 3 * 512 * 256;      // 3 x 256 x 512
    unsigned short* Wcat3 = Wcat2 + 3 * 256 * 512;      // 3 x 128 x 256
    int* deg     = (int*)(Wcat3 + 3 * 128 * 256);
    int* offs    = deg + N_NODES;
    int* cursor  = offs + N_NODES + 1;
    int* csr_src = cursor + N_NODES;
    size_t needed = (size_t)((char*)(csr_src + N_EDGES) - (char*)d_ws);
    if (ws_size < needed) return;

    // CSR build
    hipLaunchKernelGGL(zero_int_kernel, dim3((N_NODES + 255) / 256), dim3(256), 0, stream,
                       deg, N_NODES);
    hipLaunchKernelGGL(count_deg_kernel, dim3((N_EDGES + 255) / 256), dim3(256), 0, stream,
                       dst, deg, N_EDGES);
    hipLaunchKernelGGL(scan_kernel, dim3(1), dim3(SCAN_T), 0, stream, deg, offs, cursor, N_NODES);
    hipLaunchKernelGGL(scatter_kernel, dim3((N_EDGES + 255) / 256), dim3(256), 0, stream,
                       src, dst, cursor, csr_src, N_EDGES);

    // unified prep: weight transposes + x conversion in one launch
    {
        PrepJobs jb;
        const float* Ws_[9]  = {Wl1, Wr1, Ws1, Wl2, Wr2, Ws2, Wl3, Wr3, Ws3};
        unsigned short* Wt_[9] = {Wcat1, Wcat1 + 512 * 256, Wcat1 + 2 * 512 * 256,
                                  Wcat2, Wcat2 + 256 * 512, Wcat2 + 2 * 256 * 512,
                                  Wcat3, Wcat3 + 128 * 256, Wcat3 + 2 * 128 * 256};
        int K_[9] = {256, 256, 256, 512, 512, 512, 256, 256, 256};
        int D_[9] = {512, 512, 512, 256, 256, 256, 128, 128, 128};
        int o = 0;
        for (int i = 0; i < 9; ++i) {
            jb.W[i] = Ws_[i]; jb.Wt[i] = Wt_[i]; jb.K[i] = K_[i]; jb.D[i] = D_[i];
            jb.beg[i] = o; o += K_[i] * D_[i];
        }
        jb.beg[9] = o;
        jb.x = x;
        jb.xh = xhf;
        jb.nconv4 = N_NODES * 256 / 4;
        int total = o + jb.nconv4;
        hipLaunchKernelGGL(prep_kernel, dim3((total + 255) / 256), dim3(256), 0, stream, jb);
    }

    // layer 1: 256 -> 512, relu, f16 out
    run_layer(xhf, 256, 512, Wcat1, att1, bc1, bs1,
              xlh, xrh, seedh, (float*)nullptr, offs, csr_src,
              (float*)nullptr, h1h, 0, stream);
    // layer 2: 512 -> 256, relu, f16 out
    run_layer(h1h, 512, 256, Wcat2, att2, bc2, bs2,
              xlh, xrh, seedh, (float*)nullptr, offs, csr_src,
              (float*)nullptr, h2h, 0, stream);
    // layer 3: 256 -> 128, no relu, fp32 out; seed directly in d_out
    run_layer(h2h, 256, 128, Wcat3, att3, bc3, bs3,
              xlh, xrh, (unsigned short*)nullptr, (float*)d_out, offs, csr_src,
              (float*)d_out, (unsigned short*)nullptr, 1, stream);
}

// Round 13
// 365.155 us; speedup vs baseline: 1.0635x; 1.0635x over previous
//
#include <hip/hip_runtime.h>
#include <hip/hip_bf16.h>
#include <math.h>

#define N_NODES 20000
#define N_EDGES 320000

typedef _Float16 f16x8 __attribute__((ext_vector_type(8)));
typedef _Float16 h2 __attribute__((ext_vector_type(2)));
typedef float f32x4 __attribute__((ext_vector_type(4)));

__device__ __forceinline__ unsigned short f2h_bits(float f) {
    _Float16 h = (_Float16)f;            // RNE f32->f16
    return __builtin_bit_cast(unsigned short, h);
}

// async global->LDS DMA, 16B per lane; LDS dest = wave-uniform base + lane*16
typedef const unsigned int __attribute__((address_space(1)))* gas_ptr;
typedef unsigned int __attribute__((address_space(3)))* las_ptr;
__device__ __forceinline__ void gld16(const unsigned short* g, unsigned short* l) {
    __builtin_amdgcn_global_load_lds((gas_ptr)(const void*)g, (las_ptr)(void*)l, 16, 0, 0);
}

// ---------------------------------------------------------------------------
// CSR build
// ---------------------------------------------------------------------------
__global__ void zero_int_kernel(int* __restrict__ p, int n) {
    int i = blockIdx.x * blockDim.x + threadIdx.x;
    if (i < n) p[i] = 0;
}

__global__ void count_deg_kernel(const int* __restrict__ dst, int* __restrict__ deg, int E) {
    int i = blockIdx.x * blockDim.x + threadIdx.x;
    if (i < E) atomicAdd(&deg[dst[i]], 1);
}

#define SCAN_T 1024
#define SCAN_C 20   // ceil(20000/1024)
__global__ __launch_bounds__(1024) void scan_kernel(const int* __restrict__ deg,
                                                    int* __restrict__ offs,
                                                    int* __restrict__ cursor, int n) {
    __shared__ int sd[SCAN_T];
    int t = threadIdx.x;
    int base = t * SCAN_C;
    int vex[SCAN_C];
    int run = 0;
#pragma unroll
    for (int k = 0; k < SCAN_C; ++k) {
        int i = base + k;
        int d = (i < n) ? deg[i] : 0;
        vex[k] = run;
        run += d;
    }
    sd[t] = run;
    __syncthreads();
    for (int off = 1; off < SCAN_T; off <<= 1) {
        int x = (t >= off) ? sd[t - off] : 0;
        __syncthreads();
        sd[t] += x;
        __syncthreads();
    }
    int excl = sd[t] - run;
#pragma unroll
    for (int k = 0; k < SCAN_C; ++k) {
        int i = base + k;
        if (i < n) { int e = excl + vex[k]; offs[i] = e; cursor[i] = e; }
    }
    if (t == SCAN_T - 1) offs[n] = sd[t];
}

__global__ void scatter_kernel(const int* __restrict__ src, const int* __restrict__ dst,
                               int* __restrict__ cursor, int* __restrict__ csr_src, int E) {
    int i = blockIdx.x * blockDim.x + threadIdx.x;
    if (i < E) {
        int pos = atomicAdd(&cursor[dst[i]], 1);
        csr_src[pos] = src[i];
    }
}

// ---------------------------------------------------------------------------
// unified prep: 9 weight transposes (fp32 [K][D] -> f16 [D][K], output-major)
// + x fp32->f16 conversion, in ONE launch.
// ---------------------------------------------------------------------------
struct PrepJobs {
    const float* W[9];
    unsigned short* Wt[9];
    int K[9];
    int D[9];
    int beg[10];
    const float* x;            // fp32 input
    unsigned short* xh;        // f16 output
    int nconv4;                // n/4 float4 groups
};
__global__ void prep_kernel(PrepJobs jb) {
    int i = blockIdx.x * blockDim.x + threadIdx.x;
    int nt = jb.beg[9];
    if (i < nt) {
        int job = 0;
        while (i >= jb.beg[job + 1]) ++job;
        int local = i - jb.beg[job];
        int D = jb.D[job], K = jb.K[job];
        int d = local / K, k = local - d * K;
        jb.Wt[job][local] = f2h_bits(jb.W[job][(size_t)k * D + d]);
    } else {
        int c = i - nt;
        if (c < jb.nconv4) {
            int base = c * 4;
            float4 v = *(const float4*)(jb.x + base);
            uint2 pk;
            pk.x = (unsigned int)f2h_bits(v.x) | ((unsigned int)f2h_bits(v.y) << 16);
            pk.y = (unsigned int)f2h_bits(v.z) | ((unsigned int)f2h_bits(v.w) << 16);
            *(uint2*)(jb.xh + base) = pk;
        }
    }
}

// ---------------------------------------------------------------------------
// fused 3-in-1 f16 MFMA GEMM (m97 structure + XCD-aware block remap):
//   [xl | xr | seed] = A[M,K] @ Btcat[3D,K]^T  (bias bs+bc on seed segment)
// 1D grid; block g -> XCD g&7. All NC column-tiles of one M-tile on ONE XCD
// (FETCH 42 -> 14 MB measured). 128x128 tile, BK=32, 256 threads = 4 waves
// of 64x64, 16x16x32 MFMA. Staging: global_load_lds width=16, ROW-MAJOR
// chunk order (4 lanes cover one row's 64B contiguously — coalesced; the
// R12 k-major order scattered 64 lanes over 64 rows and regressed 33->54us).
// Operands swapped: mfma(Bt_frag, A_frag) -> packed 8B/16B epilogue stores.
// ---------------------------------------------------------------------------
template <int SEED_F32>
__global__ __launch_bounds__(256) void gemm3_kernel(
        const unsigned short* __restrict__ A,    // [M][K] f16
        const unsigned short* __restrict__ Bt,   // [3D][K] f16 (Wl^T|Wr^T|Ws^T)
        unsigned short* __restrict__ xlh,        // [M][D] f16
        unsigned short* __restrict__ xrh,        // [M][D] f16
        unsigned short* __restrict__ seedh,      // [M][D] f16 (SEED_F32==0)
        float* __restrict__ seedf,               // [M][D] fp32 (SEED_F32==1)
        const float* __restrict__ b1,
        const float* __restrict__ b2,
        int M, int K, int D) {
    __shared__ __align__(16) unsigned short Asl[128 * 32];
    __shared__ __align__(16) unsigned short Bsl[128 * 32];

    int NC = (3 * D) >> 7;               // column tiles
    int MT = (M + 127) >> 7;             // M tiles
    int g = blockIdx.x;
    int xcd = g & 7, slot = g >> 3;
    int m_local = slot / NC, c = slot - m_local * NC;
    int mt = m_local * 8 + xcd;
    if (mt >= MT) return;                // block-uniform -> safe before barriers

    int tid = threadIdx.x;
    int wave = tid >> 6, lane = tid & 63;
    int q = lane >> 4, t = lane & 15;
    int wm = (wave & 1) * 64, wn = (wave >> 1) * 64;
    int bm = mt << 7;
    int bn_all = c << 7;
    int seg = bn_all / D;                // D multiple of 128 -> block-uniform
    int bn = bn_all - seg * D;

    // acc[jn][im]: value reg r at lane (q,t) = C[m = im*16 + t][n = jn*16 + q*4 + r]
    f32x4 acc[4][4];
#pragma unroll
    for (int i = 0; i < 4; ++i)
#pragma unroll
        for (int j = 0; j < 4; ++j) acc[i][j] = (f32x4){0.f, 0.f, 0.f, 0.f};

    for (int k0 = 0; k0 < K; k0 += 32) {
        // A tile: 128 rows x 32 k = 512 16B chunks; 256 lanes -> 2 DMA rounds
#pragma unroll
        for (int rnd = 0; rnd < 2; ++rnd) {
            int ch = rnd * 256 + tid;
            int row = ch >> 2, part = ch & 3;
            int gr = bm + row; if (gr >= M) gr = M - 1;   // clamp, rows>=M unused
            gld16(A + (size_t)gr * K + k0 + part * 8,
                  Asl + (rnd * 256 + wave * 64) * 8);     // wave-uniform base
        }
        // Bt tile (3D multiple of 128 -> no guard)
#pragma unroll
        for (int rnd = 0; rnd < 2; ++rnd) {
            int ch = rnd * 256 + tid;
            int row = ch >> 2, part = ch & 3;
            gld16(Bt + (size_t)(bn_all + row) * K + k0 + part * 8,
                  Bsl + (rnd * 256 + wave * 64) * 8);
        }
        __syncthreads();   // drains vmcnt -> DMA complete

        f16x8 an[4], am[4];
#pragma unroll
        for (int jn = 0; jn < 4; ++jn)
            an[jn] = *(const f16x8*)(Bsl + (wn + jn * 16 + t) * 32 + q * 8);
#pragma unroll
        for (int im = 0; im < 4; ++im)
            am[im] = *(const f16x8*)(Asl + (wm + im * 16 + t) * 32 + q * 8);
#pragma unroll
        for (int jn = 0; jn < 4; ++jn)
#pragma unroll
            for (int im = 0; im < 4; ++im)
                acc[jn][im] = __builtin_amdgcn_mfma_f32_16x16x32_f16(an[jn], am[im], acc[jn][im], 0, 0, 0);
        __syncthreads();   // protect LDS before next staging
    }

    // epilogue: per lane, 4 consecutive columns per (jn,im) -> packed stores
#pragma unroll
    for (int jn = 0; jn < 4; ++jn) {
        int n0 = bn + wn + jn * 16 + q * 4;
        float bx = 0.f, by = 0.f, bz = 0.f, bw = 0.f;
        if (seg == 2) {
            float4 bb1 = *(const float4*)(b1 + n0);
            float4 bb2 = *(const float4*)(b2 + n0);
            bx = bb1.x + bb2.x; by = bb1.y + bb2.y;
            bz = bb1.z + bb2.z; bw = bb1.w + bb2.w;
        }
#pragma unroll
        for (int im = 0; im < 4; ++im) {
            int m = bm + wm + im * 16 + t;
            if (m < M) {
                float v0 = acc[jn][im][0] + bx;
                float v1 = acc[jn][im][1] + by;
                float v2 = acc[jn][im][2] + bz;
                float v3 = acc[jn][im][3] + bw;
                size_t idx = (size_t)m * D + n0;
                if (seg == 2 && SEED_F32) {
                    *(float4*)(seedf + idx) = make_float4(v0, v1, v2, v3);
                } else {
                    uint2 pk;
                    pk.x = (unsigned int)f2h_bits(v0) | ((unsigned int)f2h_bits(v1) << 16);
                    pk.y = (unsigned int)f2h_bits(v2) | ((unsigned int)f2h_bits(v3) << 16);
                    unsigned short* dstp = (seg == 0) ? xlh : (seg == 1) ? xrh : seedh;
                    *(uint2*)(dstp + idx) = pk;
                }
            }
        }
    }
}

// ---------------------------------------------------------------------------
// fused per-node (R10 variant — best measured: 53.1 µs, VGPR 44):
// edge scores + online softmax + aggregation + skip. One wave per node,
// 2 nodes per 128-thread block; 4 edges/iter; f16 packed score math +
// f32-acc dot2; 11-shuffle butterfly; index-only prefetch.
// (R11's data-pipelined variant regressed: VGPR 64, occ 33%, 55.6 µs.)
// ---------------------------------------------------------------------------
template <int D, int SEED_H, int WRITE_H, int RELU>
__global__ __launch_bounds__(128) void fused_agg_kernel(
        const unsigned short* __restrict__ xl,
        const unsigned short* __restrict__ xr,
        const float* __restrict__ att,
        const int* __restrict__ offs,
        const int* __restrict__ csr_src,
        const unsigned short* __restrict__ seedh,
        const float* __restrict__ seedf,
        float* __restrict__ outf,
        unsigned short* __restrict__ outh) {
    constexpr int VPL = D / 64;
    constexpr int HP = VPL / 2;
    typedef _Float16 hvec __attribute__((ext_vector_type(VPL)));

    int wave = threadIdx.x >> 6, lane = threadIdx.x & 63;
    int n = blockIdx.x * 2 + wave;
    if (n >= N_NODES) return;
    int beg = offs[n], end = offs[n + 1];

    h2 xr_h[HP], att_h[HP];
    hvec xrv = *(const hvec*)(xr + (size_t)n * D + lane * VPL);
#pragma unroll
    for (int pp = 0; pp < HP; ++pp) {
        xr_h[pp] = (h2){xrv[2 * pp], xrv[2 * pp + 1]};
        att_h[pp] = (h2){(_Float16)att[lane * VPL + 2 * pp],
                         (_Float16)att[lane * VPL + 2 * pp + 1]};
    }

    float acc[VPL];
#pragma unroll
    for (int v = 0; v < VPL; ++v) acc[v] = 0.f;
    float m = -INFINITY, s = 0.f;

    const _Float16 c02 = (_Float16)0.2f;
    int lb0 = lane & 1;
    int lb1 = lane & 2;

    int nfull = (end - beg) >> 2;
    int j = beg;
    int i0 = 0, i1 = 0, i2 = 0, i3 = 0;
    if (nfull > 0) {
        i0 = csr_src[beg]; i1 = csr_src[beg + 1];
        i2 = csr_src[beg + 2]; i3 = csr_src[beg + 3];
    }
    for (int b = 0; b < nfull; ++b) {
        int s0 = i0, s1 = i1, s2 = i2, s3 = i3;
        int jn4 = j + 4;
        if (b + 1 < nfull) {            // prefetch next batch's indices
            i0 = csr_src[jn4]; i1 = csr_src[jn4 + 1];
            i2 = csr_src[jn4 + 2]; i3 = csr_src[jn4 + 3];
        }
        hvec x0 = *(const hvec*)(xl + (size_t)s0 * D + lane * VPL);
        hvec x1 = *(const hvec*)(xl + (size_t)s1 * D + lane * VPL);
        hvec x2 = *(const hvec*)(xl + (size_t)s2 * D + lane * VPL);
        hvec x3 = *(const hvec*)(xl + (size_t)s3 * D + lane * VPL);
        float p0 = 0.f, p1 = 0.f, p2 = 0.f, p3 = 0.f;
#pragma unroll
        for (int pp = 0; pp < HP; ++pp) {
            h2 a0 = (h2){x0[2 * pp], x0[2 * pp + 1]};
            h2 a1 = (h2){x1[2 * pp], x1[2 * pp + 1]};
            h2 a2 = (h2){x2[2 * pp], x2[2 * pp + 1]};
            h2 a3 = (h2){x3[2 * pp], x3[2 * pp + 1]};
            h2 z0 = a0 + xr_h[pp];
            h2 z1 = a1 + xr_h[pp];
            h2 z2 = a2 + xr_h[pp];
            h2 z3 = a3 + xr_h[pp];
            h2 l0 = __builtin_elementwise_max(z0, z0 * c02);   // leaky_relu
            h2 l1 = __builtin_elementwise_max(z1, z1 * c02);
            h2 l2 = __builtin_elementwise_max(z2, z2 * c02);
            h2 l3 = __builtin_elementwise_max(z3, z3 * c02);
#if __has_builtin(__builtin_amdgcn_fdot2)
            p0 = __builtin_amdgcn_fdot2(l0, att_h[pp], p0, false);
            p1 = __builtin_amdgcn_fdot2(l1, att_h[pp], p1, false);
            p2 = __builtin_amdgcn_fdot2(l2, att_h[pp], p2, false);
            p3 = __builtin_amdgcn_fdot2(l3, att_h[pp], p3, false);
#else
            p0 += (float)l0.x * (float)att_h[pp].x + (float)l0.y * (float)att_h[pp].y;
            p1 += (float)l1.x * (float)att_h[pp].x + (float)l1.y * (float)att_h[pp].y;
            p2 += (float)l2.x * (float)att_h[pp].x + (float)l2.y * (float)att_h[pp].y;
            p3 += (float)l3.x * (float)att_h[pp].x + (float)l3.y * (float)att_h[pp].y;
#endif
        }
        // butterfly tree: stride 1 (4->2 regs), stride 2 (2->1), strides 4..32
        float k0 = lb0 ? p1 : p0, sn0 = lb0 ? p0 : p1;
        float k1 = lb0 ? p3 : p2, sn1 = lb0 ? p2 : p3;
        k0 += __shfl_xor(sn0, 1, 64);
        k1 += __shfl_xor(sn1, 1, 64);
        float k = lb1 ? k1 : k0, sn = lb1 ? k0 : k1;
        k += __shfl_xor(sn, 2, 64);
        k += __shfl_xor(k, 4, 64);
        k += __shfl_xor(k, 8, 64);
        k += __shfl_xor(k, 16, 64);
        k += __shfl_xor(k, 32, 64);
        // lane l holds full score of edge (l&3); broadcast all four
        float q0 = __shfl(k, 0, 64);
        float q1 = __shfl(k, 1, 64);
        float q2 = __shfl(k, 2, 64);
        float q3 = __shfl(k, 3, 64);

        float mn = fmaxf(m, fmaxf(fmaxf(q0, q1), fmaxf(q2, q3)));
        float sc = __expf(m - mn);           // first iter: exp(-inf)=0
        float e0 = __expf(q0 - mn);
        float e1 = __expf(q1 - mn);
        float e2 = __expf(q2 - mn);
        float e3 = __expf(q3 - mn);
        s = s * sc + e0 + e1 + e2 + e3;
#pragma unroll
        for (int v = 0; v < VPL; ++v)
            acc[v] = acc[v] * sc + e0 * (float)x0[v] + e1 * (float)x1[v]
                                 + e2 * (float)x2[v] + e3 * (float)x3[v];
        m = mn;
        j = jn4;
    }
    for (; j < end; ++j) {   // tail (0-3 edges)
        int s0 = csr_src[j];
        hvec x0 = *(const hvec*)(xl + (size_t)s0 * D + lane * VPL);
        float p0 = 0.f;
#pragma unroll
        for (int pp = 0; pp < HP; ++pp) {
            h2 a0 = (h2){x0[2 * pp], x0[2 * pp + 1]};
            h2 z0 = a0 + xr_h[pp];
            h2 l0 = __builtin_elementwise_max(z0, z0 * c02);
#if __has_builtin(__builtin_amdgcn_fdot2)
            p0 = __builtin_amdgcn_fdot2(l0, att_h[pp], p0, false);
#else
            p0 += (float)l0.x * (float)att_h[pp].x + (float)l0.y * (float)att_h[pp].y;
#endif
        }
#pragma unroll
        for (int o = 32; o > 0; o >>= 1) p0 += __shfl_xor(p0, o, 64);
        float mn = fmaxf(m, p0);
        float sc = __expf(m - mn);
        float e0 = __expf(p0 - mn);
        s = s * sc + e0;
#pragma unroll
        for (int v = 0; v < VPL; ++v) acc[v] = acc[v] * sc + e0 * (float)x0[v];
        m = mn;
    }

    float sinv = 1.0f / (s + 1e-16f);
    size_t base = (size_t)n * D + lane * VPL;
    float sd[VPL];
    if (SEED_H) {
        hvec sv = *(const hvec*)(seedh + base);
#pragma unroll
        for (int v = 0; v < VPL; ++v) sd[v] = (float)sv[v];
    } else {
#pragma unroll
        for (int v = 0; v < VPL; ++v) sd[v] = seedf[base + v];
    }
#pragma unroll
    for (int v = 0; v < VPL; ++v) {
        float val = sd[v] + acc[v] * sinv;
        if (RELU) val = fmaxf(val, 0.f);
        if (WRITE_H) outh[base + v] = f2h_bits(val);
        else         outf[base + v] = val;
    }
}

// ---------------------------------------------------------------------------
// host-side layer driver
// ---------------------------------------------------------------------------
static void run_layer(const unsigned short* hact, int K, int D,
                      const unsigned short* Wcat,
                      const float* att, const float* bc, const float* bs,
                      unsigned short* xlh, unsigned short* xrh,
                      unsigned short* seedh, float* seedf,
                      const int* offs, const int* csr_src,
                      float* outf, unsigned short* outh, int final_layer,
                      hipStream_t stream) {
    int NC = 3 * D / 128;
    int MT = (N_NODES + 127) / 128;
    int nblk = 8 * ((MT + 7) / 8) * NC;   // XCD-swizzled 1D grid
    if (final_layer)
        hipLaunchKernelGGL((gemm3_kernel<1>), dim3(nblk), dim3(256), 0, stream, hact, Wcat,
                           xlh, xrh, (unsigned short*)nullptr, seedf, bs, bc, N_NODES, K, D);
    else
        hipLaunchKernelGGL((gemm3_kernel<0>), dim3(nblk), dim3(256), 0, stream, hact, Wcat,
                           xlh, xrh, seedh, (float*)nullptr, bs, bc, N_NODES, K, D);

    dim3 agrid((N_NODES + 1) / 2);
    if (D == 512) {
        hipLaunchKernelGGL((fused_agg_kernel<512, 1, 1, 1>), agrid, dim3(128), 0, stream,
                           xlh, xrh, att, offs, csr_src, seedh, (const float*)nullptr,
                           (float*)nullptr, outh);
    } else if (D == 256) {
        hipLaunchKernelGGL((fused_agg_kernel<256, 1, 1, 1>), agrid, dim3(128), 0, stream,
                           xlh, xrh, att, offs, csr_src, seedh, (const float*)nullptr,
                           (float*)nullptr, outh);
    } else {
        hipLaunchKernelGGL((fused_agg_kernel<128, 0, 0, 0>), agrid, dim3(128), 0, stream,
                           xlh, xrh, att, offs, csr_src, (const unsigned short*)nullptr, seedf,
                           outf, (unsigned short*)nullptr);
    }
}

extern "C" void kernel_launch(void* const* d_in, const int* in_sizes, int n_in,
                              void* d_out, int out_size, void* d_ws, size_t ws_size,
                              hipStream_t stream) {
    const float* x = (const float*)d_in[0];
    const int* ei = (const int*)d_in[1];
    const int* src = ei;
    const int* dst = ei + N_EDGES;

    const float* Wl1 = (const float*)d_in[2];
    const float* Wr1 = (const float*)d_in[3];
    const float* att1 = (const float*)d_in[4];
    const float* bc1 = (const float*)d_in[5];
    const float* Ws1 = (const float*)d_in[6];
    const float* bs1 = (const float*)d_in[7];
    const float* Wl2 = (const float*)d_in[8];
    const float* Wr2 = (const float*)d_in[9];
    const float* att2 = (const float*)d_in[10];
    const float* bc2 = (const float*)d_in[11];
    const float* Ws2 = (const float*)d_in[12];
    const float* bs2 = (const float*)d_in[13];
    const float* Wl3 = (const float*)d_in[14];
    const float* Wr3 = (const float*)d_in[15];
    const float* att3 = (const float*)d_in[16];
    const float* bc3 = (const float*)d_in[17];
    const float* Ws3 = (const float*)d_in[18];
    const float* bs3 = (const float*)d_in[19];

    // workspace carve
    const size_t NF = (size_t)N_NODES * 512;
    const size_t NH = (size_t)N_NODES * 256;
    unsigned short* xlh   = (unsigned short*)d_ws;      // N x 512 f16 (reused per layer)
    unsigned short* xrh   = xlh + NF;
    unsigned short* seedh = xrh + NF;                   // N x 512 f16 (layers 1-2)
    unsigned short* xhf   = seedh + NF;                 // x as f16: N x 256
    unsigned short* h1h   = xhf + NH;                   // layer1 out: N x 512
    unsigned short* h2h   = h1h + NF;                   // layer2 out: N x 256
    unsigned short* Wcat1 = h2h + NH;                   // 3 x 512 x 256
    unsigned short* Wcat2 = Wcat1 + 3 * 512 * 256;      // 3 x 256 x 512
    unsigned short* Wcat3 = Wcat2 + 3 * 256 * 512;      // 3 x 128 x 256
    int* deg     = (int*)(Wcat3 + 3 * 128 * 256);
    int* offs    = deg + N_NODES;
    int* cursor  = offs + N_NODES + 1;
    int* csr_src = cursor + N_NODES;
    size_t needed = (size_t)((char*)(csr_src + N_EDGES) - (char*)d_ws);
    if (ws_size < needed) return;

    // CSR build
    hipLaunchKernelGGL(zero_int_kernel, dim3((N_NODES + 255) / 256), dim3(256), 0, stream,
                       deg, N_NODES);
    hipLaunchKernelGGL(count_deg_kernel, dim3((N_EDGES + 255) / 256), dim3(256), 0, stream,
                       dst, deg, N_EDGES);
    hipLaunchKernelGGL(scan_kernel, dim3(1), dim3(SCAN_T), 0, stream, deg, offs, cursor, N_NODES);
    hipLaunchKernelGGL(scatter_kernel, dim3((N_EDGES + 255) / 256), dim3(256), 0, stream,
                       src, dst, cursor, csr_src, N_EDGES);

    // unified prep: weight transposes + x conversion in one launch
    {
        PrepJobs jb;
        const float* Ws_[9]  = {Wl1, Wr1, Ws1, Wl2, Wr2, Ws2, Wl3, Wr3, Ws3};
        unsigned short* Wt_[9] = {Wcat1, Wcat1 + 512 * 256, Wcat1 + 2 * 512 * 256,
                                  Wcat2, Wcat2 + 256 * 512, Wcat2 + 2 * 256 * 512,
                                  Wcat3, Wcat3 + 128 * 256, Wcat3 + 2 * 128 * 256};
        int K_[9] = {256, 256, 256, 512, 512, 512, 256, 256, 256};
        int D_[9] = {512, 512, 512, 256, 256, 256, 128, 128, 128};
        int o = 0;
        for (int i = 0; i < 9; ++i) {
            jb.W[i] = Ws_[i]; jb.Wt[i] = Wt_[i]; jb.K[i] = K_[i]; jb.D[i] = D_[i];
            jb.beg[i] = o; o += K_[i] * D_[i];
        }
        jb.beg[9] = o;
        jb.x = x;
        jb.xh = xhf;
        jb.nconv4 = N_NODES * 256 / 4;
        int total = o + jb.nconv4;
        hipLaunchKernelGGL(prep_kernel, dim3((total + 255) / 256), dim3(256), 0, stream, jb);
    }

    // layer 1: 256 -> 512, relu, f16 out
    run_layer(xhf, 256, 512, Wcat1, att1, bc1, bs1,
              xlh, xrh, seedh, (float*)nullptr, offs, csr_src,
              (float*)nullptr, h1h, 0, stream);
    // layer 2: 512 -> 256, relu, f16 out
    run_layer(h1h, 512, 256, Wcat2, att2, bc2, bs2,
              xlh, xrh, seedh, (float*)nullptr, offs, csr_src,
              (float*)nullptr, h2h, 0, stream);
    // layer 3: 256 -> 128, no relu, fp32 out; seed directly in d_out
    run_layer(h2h, 256, 128, Wcat3, att3, bc3, bs3,
              xlh, xrh, (unsigned short*)nullptr, (float*)d_out, offs, csr_src,
              (float*)d_out, (unsigned short*)nullptr, 1, stream);
}